// Round 10
// baseline (1056.912 us; speedup 1.0000x reference)
//
#include <hip/hip_runtime.h>
#include <math.h>

// ---------------------------------------------------------------------------
// GAT (3-layer PyG GATConv, eval) on MI355X.
//   CSR build: two-level bucket sort (coalesced).
//   per layer: k_gemm = fp16 MFMA + fused logits, writes xp PLANE-MAJOR
//              (xp[plane][node][16], plane = 16-channel slice);
//              k_agg  = XCD-sliced segment softmax aggregation: slice s ->
//              XCD s via blockIdx%SLICES; per-XCD working set 3.2MB -> L2-hot.
// R10: L2-residency slicing (R9 showed gather L2-miss traffic is the wall).
// ---------------------------------------------------------------------------

#define N_NODES 100000
#define NBUCK ((N_NODES + 255) / 256)   // 391 buckets of 256 nodes
#define WT_ELEMS (16384 + 16384 + 8192) // wt0 + wt1 + wt2 elements
#define WT_TOT (WT_ELEMS + NBUCK)       // + bucketCnt zeroing

typedef __attribute__((ext_vector_type(4))) _Float16 half4;
typedef __attribute__((ext_vector_type(8))) _Float16 half8;
typedef __attribute__((ext_vector_type(4))) float f32x4;

// fma_mix: alo += s * f16lo(u); ahi += s * f16hi(u)   (exact: f16 widened)
__device__ inline void fmamix2(float& alo, float& ahi, float s, unsigned u) {
    asm("v_fma_mix_f32 %0, %1, %2, %0 op_sel_hi:[0,1,0]" : "+v"(alo) : "v"(s), "v"(u));
    asm("v_fma_mix_f32 %0, %1, %2, %0 op_sel:[0,1,0] op_sel_hi:[0,1,0]" : "+v"(ahi) : "v"(s), "v"(u));
}

// ------------------------------ CSR build ----------------------------------

__global__ __launch_bounds__(256) void k_bcount(const int* __restrict__ ei, int E, int ETOT,
                                                int* __restrict__ bucketCnt) {
    __shared__ int h[NBUCK];
    for (int b = threadIdx.x; b < NBUCK; b += 256) h[b] = 0;
    __syncthreads();
    const int base = blockIdx.x * 4096;
#pragma unroll
    for (int j = 0; j < 16; ++j) {
        int idx = base + j * 256 + threadIdx.x;
        if (idx < ETOT) {
            int dst = (idx < E) ? ei[E + idx] : (idx - E);
            atomicAdd(&h[dst >> 8], 1);
        }
    }
    __syncthreads();
    for (int b = threadIdx.x; b < NBUCK; b += 256)
        if (h[b]) atomicAdd(&bucketCnt[b], h[b]);
}

__global__ __launch_bounds__(256) void k_bscan(const int* __restrict__ bucketCnt,
                                               int* __restrict__ bstart,
                                               int* __restrict__ gcur, int ETOT) {
    __shared__ int lds[512];
    const int t = threadIdx.x;
    lds[t] = (t < NBUCK) ? bucketCnt[t] : 0;
    lds[t + 256] = (t + 256 < NBUCK) ? bucketCnt[t + 256] : 0;
    __syncthreads();
    for (int d = 1; d < 512; d <<= 1) {
        int v0 = (t >= d) ? lds[t - d] : 0;
        int v1 = (t + 256 >= d) ? lds[t + 256 - d] : 0;
        __syncthreads();
        lds[t] += v0;
        lds[t + 256] += v1;
        __syncthreads();
    }
    int e0 = (t == 0) ? 0 : lds[t - 1];
    int e1 = lds[t + 255];
    if (t < NBUCK)       { bstart[t] = e0;       gcur[t] = e0; }
    if (t + 256 < NBUCK) { bstart[t + 256] = e1; gcur[t + 256] = e1; }
    if (t == 0) bstart[NBUCK] = ETOT;
}

__global__ __launch_bounds__(256) void k_bplace(const int* __restrict__ ei, int E, int ETOT,
                                                int* __restrict__ gcur, int* __restrict__ tmp) {
    __shared__ int h[NBUCK];
    __shared__ int cur[NBUCK];
    for (int b = threadIdx.x; b < NBUCK; b += 256) h[b] = 0;
    __syncthreads();
    const int base = blockIdx.x * 4096;
    int pk[16], bk[16];
#pragma unroll
    for (int j = 0; j < 16; ++j) {
        int idx = base + j * 256 + threadIdx.x;
        bk[j] = -1;
        if (idx < ETOT) {
            int s, d;
            if (idx < E) { s = ei[idx]; d = ei[E + idx]; }
            else         { s = idx - E; d = idx - E; }
            bk[j] = d >> 8;
            pk[j] = s | ((d & 255) << 17);
            atomicAdd(&h[bk[j]], 1);
        }
    }
    __syncthreads();
    for (int b = threadIdx.x; b < NBUCK; b += 256)
        cur[b] = h[b] ? atomicAdd(&gcur[b], h[b]) : 0;
    __syncthreads();
#pragma unroll
    for (int j = 0; j < 16; ++j) {
        if (bk[j] >= 0) {
            int pos = atomicAdd(&cur[bk[j]], 1);
            tmp[pos] = pk[j];
        }
    }
}

__global__ __launch_bounds__(256) void k_bfinal(const int* __restrict__ tmp,
                                                const int* __restrict__ bstart,
                                                int* __restrict__ rowptr,
                                                int* __restrict__ ssrc, int N) {
    __shared__ int cnt[256];
    __shared__ int cur[256];
    const int t = threadIdx.x;
    const int b = blockIdx.x;
    const int s0 = bstart[b], s1 = bstart[b + 1];
    cnt[t] = 0;
    __syncthreads();
    for (int e = s0 + t; e < s1; e += 256)
        atomicAdd(&cnt[tmp[e] >> 17], 1);
    __syncthreads();
    int c0 = cnt[t];
    for (int d = 1; d < 256; d <<= 1) {
        int v = (t >= d) ? cnt[t - d] : 0;
        __syncthreads();
        cnt[t] += v;
        __syncthreads();
    }
    int excl = cnt[t] - c0;
    int node = b * 256 + t;
    if (node <= N) rowptr[node] = s0 + excl;
    cur[t] = excl;
    __syncthreads();
    for (int e = s0 + t; e < s1; e += 256) {
        int p = tmp[e];
        int pos = atomicAdd(&cur[p >> 17], 1);
        ssrc[s0 + pos] = p & 0x1FFFF;
    }
}

// ------------------- W transposes to fp16 (+ bucketCnt zero) ----------------
__global__ void k_wt3(const float* __restrict__ W0, const float* __restrict__ W1,
                      const float* __restrict__ W2, _Float16* __restrict__ wt0,
                      _Float16* __restrict__ wt1, _Float16* __restrict__ wt2,
                      int* __restrict__ bucketCnt) {
    int idx = blockIdx.x * 256 + threadIdx.x;
    if (idx < 16384) {
        int k = idx >> 7, n = idx & 127;
        wt0[n * 128 + k] = (_Float16)W0[idx];
    } else if (idx < 32768) {
        int i = idx - 16384;
        int k = i >> 7, n = i & 127;
        wt1[n * 128 + k] = (_Float16)W1[i];
    } else if (idx < WT_ELEMS) {
        int i = idx - 32768;
        int k = i >> 6, n = i & 63;
        wt2[n * 128 + k] = (_Float16)W2[i];
    } else if (idx < WT_TOT) {
        bucketCnt[idx - WT_ELEMS] = 0;
    }
}

// ------------------------------ MFMA GEMM + logits --------------------------
// xp written PLANE-MAJOR: XP[plane][node][16], plane = nt (16-channel slice).
template <int OUT, int H, bool INF16>
__global__ __launch_bounds__(256) void k_gemm(const void* __restrict__ Xv_,
                                              const _Float16* __restrict__ Wt,
                                              const float* __restrict__ a_src,
                                              const float* __restrict__ a_dst,
                                              _Float16* __restrict__ XP,
                                              float* __restrict__ al_s,
                                              float* __restrict__ al_d, int N) {
    constexpr int NT = OUT / 16;
    constexpr int C = OUT / H;
    constexpr int LDH = 136;
    __shared__ _Float16 As[64 * LDH];
    __shared__ _Float16 Ws[OUT * LDH];
    const int tid = threadIdx.x;
    const int row0 = blockIdx.x * 64;

    for (int c = tid; c < OUT * 16; c += 256) {
        int r = c >> 4, kc = c & 15;
        *(half8*)&Ws[r * LDH + kc * 8] = *(const half8*)(Wt + r * 128 + kc * 8);
    }
    for (int c = tid; c < 64 * 16; c += 256) {
        int r = c >> 4, kc = c & 15;
        int grow = row0 + r;
        half8 hv;
        if (grow < N) {
            if constexpr (INF16) {
                hv = *(const half8*)((const _Float16*)Xv_ + (size_t)grow * 128 + kc * 8);
            } else {
                const float4* xr = (const float4*)((const float*)Xv_ + (size_t)grow * 128 + kc * 8);
                float4 x0 = xr[0], x1 = xr[1];
                hv[0] = (_Float16)x0.x; hv[1] = (_Float16)x0.y;
                hv[2] = (_Float16)x0.z; hv[3] = (_Float16)x0.w;
                hv[4] = (_Float16)x1.x; hv[5] = (_Float16)x1.y;
                hv[6] = (_Float16)x1.z; hv[7] = (_Float16)x1.w;
            }
        } else {
#pragma unroll
            for (int j = 0; j < 8; ++j) hv[j] = (_Float16)0.f;
        }
        *(half8*)&As[r * LDH + kc * 8] = hv;
    }
    __syncthreads();

    const int w = tid >> 6;
    const int l = tid & 63;
    const int lm = l & 15;
    const int lk = l >> 4;

    f32x4 acc[NT];
#pragma unroll
    for (int nt = 0; nt < NT; ++nt) acc[nt] = {0.f, 0.f, 0.f, 0.f};

#pragma unroll
    for (int ks = 0; ks < 4; ++ks) {
        half8 av = *(const half8*)&As[(w * 16 + lm) * LDH + ks * 32 + lk * 8];
#pragma unroll
        for (int nt = 0; nt < NT; ++nt) {
            half8 bv = *(const half8*)&Ws[(nt * 16 + lm) * LDH + ks * 32 + lk * 8];
            acc[nt] = __builtin_amdgcn_mfma_f32_16x16x32_f16(av, bv, acc[nt], 0, 0, 0);
        }
    }

    float avs[NT], avd[NT];
#pragma unroll
    for (int nt = 0; nt < NT; ++nt) {
        avs[nt] = a_src[nt * 16 + lm];
        avd[nt] = a_dst[nt * 16 + lm];
    }

#pragma unroll
    for (int r = 0; r < 4; ++r) {
        int grow = row0 + w * 16 + lk * 4 + r;
        bool ok = grow < N;
#pragma unroll
        for (int nt = 0; nt < NT; ++nt)
            if (ok) XP[(size_t)nt * N * 16 + (size_t)grow * 16 + lm] = (_Float16)acc[nt][r];

        float ps[H], pd[H];
#pragma unroll
        for (int h = 0; h < H; ++h) { ps[h] = 0.f; pd[h] = 0.f; }
#pragma unroll
        for (int nt = 0; nt < NT; ++nt) {
            int h = (nt * 16) / C;
            ps[h] += acc[nt][r] * avs[nt];
            pd[h] += acc[nt][r] * avd[nt];
        }
#pragma unroll
        for (int h = 0; h < H; ++h) {
#pragma unroll
            for (int o = 8; o >= 1; o >>= 1) {
                ps[h] += __shfl_xor(ps[h], o);
                pd[h] += __shfl_xor(pd[h], o);
            }
        }
        if (ok && lm == 0) {
#pragma unroll
            for (int h = 0; h < H; ++h) {
                al_s[(size_t)grow * H + h] = ps[h];
                al_d[(size_t)grow * H + h] = pd[h];
            }
        }
    }
}

// --------------------------- sliced softmax + aggregate ---------------------
// Grid = nodeGroups x SLICES; slice = blockIdx & (SLICES-1) -> pinned to one
// XCD (blockIdx%8 round-robin). Each wave: one node, 32 edge-slots x 2 lanes,
// reading 16B of plane[slice] per lane. Per-XCD plane = 3.2MB -> L2-resident.
template <int OUT, int H, bool ELU, bool OUTF16>
__global__ __launch_bounds__(256) void k_agg(const _Float16* __restrict__ xp,
                                             const float* __restrict__ al_s,
                                             const float* __restrict__ al_d,
                                             const int* __restrict__ rowptr,
                                             const int* __restrict__ ssrc,
                                             const float* __restrict__ bias,
                                             void* __restrict__ out_, int N) {
    constexpr int SLICES = OUT / 16;
    constexpr int C = OUT / H;
    const int slice = blockIdx.x & (SLICES - 1);
    const int ng = blockIdx.x / SLICES;
    const int wid = threadIdx.x >> 6;
    const int lane = threadIdx.x & 63;
    const int el = lane >> 1;   // edge slot 0..31
    const int lh = lane & 1;    // which 16B half of the 32B slice
    const int node = ng * 4 + wid;
    if (node >= N) return;
    const int rs = rowptr[node];
    const int re = rowptr[node + 1];

    const int head = (H == 1) ? 0 : (slice >> 1);   // slice spans one head (C=32)
    const int c0 = slice * 16 + lh * 8;
    const float adh = al_d[(unsigned)node * H + head];
    const _Float16* xps = xp + (size_t)slice * ((size_t)N * 16) + lh * 8;

    float ssum = 0.f;
    float acc[8];
#pragma unroll
    for (int j = 0; j < 8; ++j) acc[j] = 0.f;

    auto edge = [&](int idx) {
        int s = ssrc[idx];
        float e = al_s[(unsigned)s * H + head] + adh;
        e = e > 0.f ? e : 0.2f * e;
        float a = __expf(e);
        ssum += a;
        uint4 u = *(const uint4*)(xps + (size_t)s * 16);
        fmamix2(acc[0], acc[1], a, u.x);
        fmamix2(acc[2], acc[3], a, u.y);
        fmamix2(acc[4], acc[5], a, u.z);
        fmamix2(acc[6], acc[7], a, u.w);
    };

    int i = rs;
    for (; i + 32 <= re; i += 32) edge(i + el);
    if (i + el < re) edge(i + el);

    // reduce: ssum over all 64 lanes (each edge counted twice -> x0.5);
    // acc over edge slots (xor 2..32), preserving lh.
#pragma unroll
    for (int o = 1; o <= 32; o <<= 1) ssum += __shfl_xor(ssum, o);
    ssum *= 0.5f;
#pragma unroll
    for (int j = 0; j < 8; ++j) {
#pragma unroll
        for (int o = 2; o <= 32; o <<= 1) acc[j] += __shfl_xor(acc[j], o);
    }

    if (el == 0) {  // lanes 0 (lh=0) and 1 (lh=1)
        float inv = 1.f / (ssum + 1e-16f);
        float o[8];
#pragma unroll
        for (int j = 0; j < 8; ++j) {
            o[j] = acc[j] * inv + bias[c0 + j];
            if constexpr (ELU) o[j] = o[j] > 0.f ? o[j] : (__expf(o[j]) - 1.f);
        }
        if constexpr (OUTF16) {
            _Float16* op = (_Float16*)out_ + (size_t)node * OUT + c0;
            half8 hv;
#pragma unroll
            for (int j = 0; j < 8; ++j) hv[j] = (_Float16)o[j];
            *(half8*)op = hv;
        } else {
            float* op = (float*)out_ + (size_t)node * OUT + c0;
            *(float4*)op = make_float4(o[0], o[1], o[2], o[3]);
            *(float4*)(op + 4) = make_float4(o[4], o[5], o[6], o[7]);
        }
    }
}

// ------------------------------ launch --------------------------------------

extern "C" void kernel_launch(void* const* d_in, const int* in_sizes, int n_in,
                              void* d_out, int out_size, void* d_ws, size_t ws_size,
                              hipStream_t stream) {
    const int N = N_NODES;
    const float* x     = (const float*)d_in[0];
    const int*   ei    = (const int*)d_in[1];
    const float* W0    = (const float*)d_in[2];
    const float* as0   = (const float*)d_in[3];
    const float* ad0   = (const float*)d_in[4];
    const float* b0    = (const float*)d_in[5];
    const float* W1    = (const float*)d_in[6];
    const float* as1   = (const float*)d_in[7];
    const float* ad1   = (const float*)d_in[8];
    const float* b1    = (const float*)d_in[9];
    const float* W2    = (const float*)d_in[10];
    const float* as2   = (const float*)d_in[11];
    const float* ad2   = (const float*)d_in[12];
    const float* b2    = (const float*)d_in[13];
    float* out = (float*)d_out;

    const int E = in_sizes[1] / 2;
    const int ETOT = E + N;

    char* p = (char*)d_ws;
    auto alloc = [&](size_t bytes) {
        void* r = (void*)p;
        p += (bytes + 255) & ~(size_t)255;
        return r;
    };
    _Float16* xp    = (_Float16*)alloc((size_t)N * 128 * 2);
    _Float16* hbuf  = (_Float16*)alloc((size_t)N * 128 * 2);
    float* als      = (float*)alloc((size_t)N * 4 * 4);
    float* ald      = (float*)alloc((size_t)N * 4 * 4);
    int*   rowptr   = (int*)alloc((size_t)(N + 1) * 4);
    int*   ssrc     = (int*)alloc((size_t)ETOT * 4);
    int*   tmp      = (int*)alloc((size_t)ETOT * 4);
    int*   bucketCnt= (int*)alloc((size_t)NBUCK * 4);
    int*   bstart   = (int*)alloc((size_t)(NBUCK + 1) * 4);
    int*   gcur     = (int*)alloc((size_t)NBUCK * 4);
    _Float16* wt0   = (_Float16*)alloc((size_t)128 * 128 * 2);
    _Float16* wt1   = (_Float16*)alloc((size_t)128 * 128 * 2);
    _Float16* wt2   = (_Float16*)alloc((size_t)128 * 64 * 2);

    // ---- W transposes + bucketCnt zeroing ----
    k_wt3<<<(WT_TOT + 255) / 256, 256, 0, stream>>>(W0, W1, W2, wt0, wt1, wt2, bucketCnt);

    // ---- CSR build (bucket sort) ----
    const int PB = (ETOT + 4095) / 4096;
    k_bcount<<<PB, 256, 0, stream>>>(ei, E, ETOT, bucketCnt);
    k_bscan<<<1, 256, 0, stream>>>(bucketCnt, bstart, gcur, ETOT);
    k_bplace<<<PB, 256, 0, stream>>>(ei, E, ETOT, gcur, tmp);
    k_bfinal<<<NBUCK, 256, 0, stream>>>(tmp, bstart, rowptr, ssrc, N);

    const int gGemm = (N + 63) / 64;
    const int ngrp  = (N + 3) / 4;

    // ---- layer 0: 128 -> 4x32, ELU ----
    k_gemm<128, 4, false><<<gGemm, 256, 0, stream>>>(x, wt0, as0, ad0, xp, als, ald, N);
    k_agg<128, 4, true, true><<<ngrp * 8, 256, 0, stream>>>(xp, als, ald, rowptr, ssrc, b0, hbuf, N);

    // ---- layer 1: 128 -> 4x32, ELU ----
    k_gemm<128, 4, true><<<gGemm, 256, 0, stream>>>(hbuf, wt1, as1, ad1, xp, als, ald, N);
    k_agg<128, 4, true, true><<<ngrp * 8, 256, 0, stream>>>(xp, als, ald, rowptr, ssrc, b1, hbuf, N);

    // ---- layer 2: 128 -> 1x64, no ELU ----
    k_gemm<64, 1, true><<<gGemm, 256, 0, stream>>>(hbuf, wt2, as2, ad2, xp, als, ald, N);
    k_agg<64, 1, false, false><<<ngrp * 4, 256, 0, stream>>>(xp, als, ald, rowptr, ssrc, b2, out, N);
}

// Round 11
// 385.704 us; speedup vs baseline: 2.7402x; 2.7402x over previous
//
#include <hip/hip_runtime.h>
#include <math.h>

// ---------------------------------------------------------------------------
// GAT (3-layer PyG GATConv, eval) on MI355X.
//   CSR build: two-level bucket sort (coalesced).
//   per layer: k_gemm = fp16 MFMA + fused logits, xp stored HALF-PLANE-MAJOR
//              (xp[half][node][OUT/2]);
//              k_agg  = segment softmax aggregation over ONE channel-half per
//              launch (2 sequential launches/layer -> 12.8MB gather working
//              set, global phase separation for L2 residency).
// R11: R10's XCD slicing reverted (latency collapse + pinning failed);
//      temporal channel-halving instead.
// ---------------------------------------------------------------------------

#define N_NODES 100000
#define NBUCK ((N_NODES + 255) / 256)   // 391 buckets of 256 nodes
#define WT_ELEMS (16384 + 16384 + 8192) // wt0 + wt1 + wt2 elements
#define WT_TOT (WT_ELEMS + NBUCK)       // + bucketCnt zeroing

typedef __attribute__((ext_vector_type(4))) _Float16 half4;
typedef __attribute__((ext_vector_type(8))) _Float16 half8;
typedef __attribute__((ext_vector_type(4))) float f32x4;

// fma_mix: alo += s * f16lo(u); ahi += s * f16hi(u)   (exact: f16 widened)
__device__ inline void fmamix2(float& alo, float& ahi, float s, unsigned u) {
    asm("v_fma_mix_f32 %0, %1, %2, %0 op_sel_hi:[0,1,0]" : "+v"(alo) : "v"(s), "v"(u));
    asm("v_fma_mix_f32 %0, %1, %2, %0 op_sel:[0,1,0] op_sel_hi:[0,1,0]" : "+v"(ahi) : "v"(s), "v"(u));
}

// ------------------------------ CSR build ----------------------------------

__global__ __launch_bounds__(256) void k_bcount(const int* __restrict__ ei, int E, int ETOT,
                                                int* __restrict__ bucketCnt) {
    __shared__ int h[NBUCK];
    for (int b = threadIdx.x; b < NBUCK; b += 256) h[b] = 0;
    __syncthreads();
    const int base = blockIdx.x * 4096;
#pragma unroll
    for (int j = 0; j < 16; ++j) {
        int idx = base + j * 256 + threadIdx.x;
        if (idx < ETOT) {
            int dst = (idx < E) ? ei[E + idx] : (idx - E);
            atomicAdd(&h[dst >> 8], 1);
        }
    }
    __syncthreads();
    for (int b = threadIdx.x; b < NBUCK; b += 256)
        if (h[b]) atomicAdd(&bucketCnt[b], h[b]);
}

__global__ __launch_bounds__(256) void k_bscan(const int* __restrict__ bucketCnt,
                                               int* __restrict__ bstart,
                                               int* __restrict__ gcur, int ETOT) {
    __shared__ int lds[512];
    const int t = threadIdx.x;
    lds[t] = (t < NBUCK) ? bucketCnt[t] : 0;
    lds[t + 256] = (t + 256 < NBUCK) ? bucketCnt[t + 256] : 0;
    __syncthreads();
    for (int d = 1; d < 512; d <<= 1) {
        int v0 = (t >= d) ? lds[t - d] : 0;
        int v1 = (t + 256 >= d) ? lds[t + 256 - d] : 0;
        __syncthreads();
        lds[t] += v0;
        lds[t + 256] += v1;
        __syncthreads();
    }
    int e0 = (t == 0) ? 0 : lds[t - 1];
    int e1 = lds[t + 255];
    if (t < NBUCK)       { bstart[t] = e0;       gcur[t] = e0; }
    if (t + 256 < NBUCK) { bstart[t + 256] = e1; gcur[t + 256] = e1; }
    if (t == 0) bstart[NBUCK] = ETOT;
}

__global__ __launch_bounds__(256) void k_bplace(const int* __restrict__ ei, int E, int ETOT,
                                                int* __restrict__ gcur, int* __restrict__ tmp) {
    __shared__ int h[NBUCK];
    __shared__ int cur[NBUCK];
    for (int b = threadIdx.x; b < NBUCK; b += 256) h[b] = 0;
    __syncthreads();
    const int base = blockIdx.x * 4096;
    int pk[16], bk[16];
#pragma unroll
    for (int j = 0; j < 16; ++j) {
        int idx = base + j * 256 + threadIdx.x;
        bk[j] = -1;
        if (idx < ETOT) {
            int s, d;
            if (idx < E) { s = ei[idx]; d = ei[E + idx]; }
            else         { s = idx - E; d = idx - E; }
            bk[j] = d >> 8;
            pk[j] = s | ((d & 255) << 17);
            atomicAdd(&h[bk[j]], 1);
        }
    }
    __syncthreads();
    for (int b = threadIdx.x; b < NBUCK; b += 256)
        cur[b] = h[b] ? atomicAdd(&gcur[b], h[b]) : 0;
    __syncthreads();
#pragma unroll
    for (int j = 0; j < 16; ++j) {
        if (bk[j] >= 0) {
            int pos = atomicAdd(&cur[bk[j]], 1);
            tmp[pos] = pk[j];
        }
    }
}

__global__ __launch_bounds__(256) void k_bfinal(const int* __restrict__ tmp,
                                                const int* __restrict__ bstart,
                                                int* __restrict__ rowptr,
                                                int* __restrict__ ssrc, int N) {
    __shared__ int cnt[256];
    __shared__ int cur[256];
    const int t = threadIdx.x;
    const int b = blockIdx.x;
    const int s0 = bstart[b], s1 = bstart[b + 1];
    cnt[t] = 0;
    __syncthreads();
    for (int e = s0 + t; e < s1; e += 256)
        atomicAdd(&cnt[tmp[e] >> 17], 1);
    __syncthreads();
    int c0 = cnt[t];
    for (int d = 1; d < 256; d <<= 1) {
        int v = (t >= d) ? cnt[t - d] : 0;
        __syncthreads();
        cnt[t] += v;
        __syncthreads();
    }
    int excl = cnt[t] - c0;
    int node = b * 256 + t;
    if (node <= N) rowptr[node] = s0 + excl;
    cur[t] = excl;
    __syncthreads();
    for (int e = s0 + t; e < s1; e += 256) {
        int p = tmp[e];
        int pos = atomicAdd(&cur[p >> 17], 1);
        ssrc[s0 + pos] = p & 0x1FFFF;
    }
}

// ------------------- W transposes to fp16 (+ bucketCnt zero) ----------------
__global__ void k_wt3(const float* __restrict__ W0, const float* __restrict__ W1,
                      const float* __restrict__ W2, _Float16* __restrict__ wt0,
                      _Float16* __restrict__ wt1, _Float16* __restrict__ wt2,
                      int* __restrict__ bucketCnt) {
    int idx = blockIdx.x * 256 + threadIdx.x;
    if (idx < 16384) {
        int k = idx >> 7, n = idx & 127;
        wt0[n * 128 + k] = (_Float16)W0[idx];
    } else if (idx < 32768) {
        int i = idx - 16384;
        int k = i >> 7, n = i & 127;
        wt1[n * 128 + k] = (_Float16)W1[i];
    } else if (idx < WT_ELEMS) {
        int i = idx - 32768;
        int k = i >> 6, n = i & 63;
        wt2[n * 128 + k] = (_Float16)W2[i];
    } else if (idx < WT_TOT) {
        bucketCnt[idx - WT_ELEMS] = 0;
    }
}

// ------------------------------ MFMA GEMM + logits --------------------------
// xp written HALF-PLANE-MAJOR: XP[half][node][HC], HC = OUT/2.
template <int OUT, int H, bool INF16>
__global__ __launch_bounds__(256) void k_gemm(const void* __restrict__ Xv_,
                                              const _Float16* __restrict__ Wt,
                                              const float* __restrict__ a_src,
                                              const float* __restrict__ a_dst,
                                              _Float16* __restrict__ XP,
                                              float* __restrict__ al_s,
                                              float* __restrict__ al_d, int N) {
    constexpr int NT = OUT / 16;
    constexpr int C = OUT / H;
    constexpr int HC = OUT / 2;    // channels per half-plane
    constexpr int NTH = HC / 16;   // n-tiles per half (4 or 2)
    constexpr int LDH = 136;
    __shared__ _Float16 As[64 * LDH];
    __shared__ _Float16 Ws[OUT * LDH];
    const int tid = threadIdx.x;
    const int row0 = blockIdx.x * 64;

    for (int c = tid; c < OUT * 16; c += 256) {
        int r = c >> 4, kc = c & 15;
        *(half8*)&Ws[r * LDH + kc * 8] = *(const half8*)(Wt + r * 128 + kc * 8);
    }
    for (int c = tid; c < 64 * 16; c += 256) {
        int r = c >> 4, kc = c & 15;
        int grow = row0 + r;
        half8 hv;
        if (grow < N) {
            if constexpr (INF16) {
                hv = *(const half8*)((const _Float16*)Xv_ + (size_t)grow * 128 + kc * 8);
            } else {
                const float4* xr = (const float4*)((const float*)Xv_ + (size_t)grow * 128 + kc * 8);
                float4 x0 = xr[0], x1 = xr[1];
                hv[0] = (_Float16)x0.x; hv[1] = (_Float16)x0.y;
                hv[2] = (_Float16)x0.z; hv[3] = (_Float16)x0.w;
                hv[4] = (_Float16)x1.x; hv[5] = (_Float16)x1.y;
                hv[6] = (_Float16)x1.z; hv[7] = (_Float16)x1.w;
            }
        } else {
#pragma unroll
            for (int j = 0; j < 8; ++j) hv[j] = (_Float16)0.f;
        }
        *(half8*)&As[r * LDH + kc * 8] = hv;
    }
    __syncthreads();

    const int w = tid >> 6;
    const int l = tid & 63;
    const int lm = l & 15;
    const int lk = l >> 4;

    f32x4 acc[NT];
#pragma unroll
    for (int nt = 0; nt < NT; ++nt) acc[nt] = {0.f, 0.f, 0.f, 0.f};

#pragma unroll
    for (int ks = 0; ks < 4; ++ks) {
        half8 av = *(const half8*)&As[(w * 16 + lm) * LDH + ks * 32 + lk * 8];
#pragma unroll
        for (int nt = 0; nt < NT; ++nt) {
            half8 bv = *(const half8*)&Ws[(nt * 16 + lm) * LDH + ks * 32 + lk * 8];
            acc[nt] = __builtin_amdgcn_mfma_f32_16x16x32_f16(av, bv, acc[nt], 0, 0, 0);
        }
    }

    float avs[NT], avd[NT];
#pragma unroll
    for (int nt = 0; nt < NT; ++nt) {
        avs[nt] = a_src[nt * 16 + lm];
        avd[nt] = a_dst[nt * 16 + lm];
    }

#pragma unroll
    for (int r = 0; r < 4; ++r) {
        int grow = row0 + w * 16 + lk * 4 + r;
        bool ok = grow < N;
#pragma unroll
        for (int nt = 0; nt < NT; ++nt)
            if (ok) XP[(size_t)(nt / NTH) * N * HC + (size_t)grow * HC + (nt % NTH) * 16 + lm] =
                        (_Float16)acc[nt][r];

        float ps[H], pd[H];
#pragma unroll
        for (int h = 0; h < H; ++h) { ps[h] = 0.f; pd[h] = 0.f; }
#pragma unroll
        for (int nt = 0; nt < NT; ++nt) {
            int h = (nt * 16) / C;
            ps[h] += acc[nt][r] * avs[nt];
            pd[h] += acc[nt][r] * avd[nt];
        }
#pragma unroll
        for (int h = 0; h < H; ++h) {
#pragma unroll
            for (int o = 8; o >= 1; o >>= 1) {
                ps[h] += __shfl_xor(ps[h], o);
                pd[h] += __shfl_xor(pd[h], o);
            }
        }
        if (ok && lm == 0) {
#pragma unroll
            for (int h = 0; h < H; ++h) {
                al_s[(size_t)grow * H + h] = ps[h];
                al_d[(size_t)grow * H + h] = pd[h];
            }
        }
    }
}

// --------------------- half-plane softmax + aggregate -----------------------
// One launch per channel-half (hp = 0/1). One wave per node; edge-groups of
// GL = HC/8 lanes x 16B cover the HC-channel half-row; NG = 64/GL edges in
// flight per trip, 2-unrolled. Per-lane head alpha recompute (exact softmax:
// denominator is full-edge sum, computed per head via group reduction).
template <int OUT, int H, bool ELU, bool OUTF16>
__global__ __launch_bounds__(256) void k_agg(const _Float16* __restrict__ xp,
                                             const float* __restrict__ al_s,
                                             const float* __restrict__ al_d,
                                             const int* __restrict__ rowptr,
                                             const int* __restrict__ ssrc,
                                             const float* __restrict__ bias,
                                             void* __restrict__ out_, int N, int hp) {
    constexpr int C = OUT / H;
    constexpr int HC = OUT / 2;   // channels this launch
    constexpr int GL = HC / 8;    // lanes per edge-group (8 or 4)
    constexpr int NG = 64 / GL;   // edge-groups per wave (8 or 16)
    const int wid = threadIdx.x >> 6;
    const int lane = threadIdx.x & 63;
    const int g = lane / GL;      // edge-group id
    const int cl = lane % GL;     // channel-lane within group
    const int node = blockIdx.x * 4 + wid;
    if (node >= N) return;
    const int rs = rowptr[node];
    const int re = rowptr[node + 1];

    const int c0h = cl * 8;                 // channel offset within half-plane
    const int c0g = hp * HC + c0h;          // global channel offset
    const int head = (H == 1) ? 0 : (c0g / C);
    const float adh = al_d[(unsigned)node * H + head];
    const _Float16* xps = xp + (size_t)hp * N * HC + c0h;

    float ssum = 0.f;
    float acc[8];
#pragma unroll
    for (int j = 0; j < 8; ++j) acc[j] = 0.f;

    auto edge = [&](int idx) {
        int s = ssrc[idx];
        float e = al_s[(unsigned)s * H + head] + adh;
        e = e > 0.f ? e : 0.2f * e;
        float a = __expf(e);
        ssum += a;
        uint4 u = *(const uint4*)(xps + (size_t)s * HC);
        fmamix2(acc[0], acc[1], a, u.x);
        fmamix2(acc[2], acc[3], a, u.y);
        fmamix2(acc[4], acc[5], a, u.z);
        fmamix2(acc[6], acc[7], a, u.w);
    };

    int i = rs;
    for (; i + 2 * NG <= re; i += 2 * NG) { edge(i + g); edge(i + g + NG); }
    for (; i + NG <= re; i += NG) edge(i + g);
    if (i + g < re) edge(i + g);

    // reduce across edge-groups (cl preserved -> per-head sums stay separate)
#pragma unroll
    for (int o = GL; o <= 32; o <<= 1) {
        ssum += __shfl_xor(ssum, o);
#pragma unroll
        for (int j = 0; j < 8; ++j) acc[j] += __shfl_xor(acc[j], o);
    }

    if (g == 0) {   // lanes 0..GL-1 write 8 channels each
        float inv = 1.f / (ssum + 1e-16f);
        float o[8];
#pragma unroll
        for (int j = 0; j < 8; ++j) {
            o[j] = acc[j] * inv + bias[c0g + j];
            if constexpr (ELU) o[j] = o[j] > 0.f ? o[j] : (__expf(o[j]) - 1.f);
        }
        if constexpr (OUTF16) {
            _Float16* op = (_Float16*)out_ + (size_t)node * OUT + c0g;
            half8 hv;
#pragma unroll
            for (int j = 0; j < 8; ++j) hv[j] = (_Float16)o[j];
            *(half8*)op = hv;
        } else {
            float* op = (float*)out_ + (size_t)node * OUT + c0g;
            *(float4*)op = make_float4(o[0], o[1], o[2], o[3]);
            *(float4*)(op + 4) = make_float4(o[4], o[5], o[6], o[7]);
        }
    }
}

// ------------------------------ launch --------------------------------------

extern "C" void kernel_launch(void* const* d_in, const int* in_sizes, int n_in,
                              void* d_out, int out_size, void* d_ws, size_t ws_size,
                              hipStream_t stream) {
    const int N = N_NODES;
    const float* x     = (const float*)d_in[0];
    const int*   ei    = (const int*)d_in[1];
    const float* W0    = (const float*)d_in[2];
    const float* as0   = (const float*)d_in[3];
    const float* ad0   = (const float*)d_in[4];
    const float* b0    = (const float*)d_in[5];
    const float* W1    = (const float*)d_in[6];
    const float* as1   = (const float*)d_in[7];
    const float* ad1   = (const float*)d_in[8];
    const float* b1    = (const float*)d_in[9];
    const float* W2    = (const float*)d_in[10];
    const float* as2   = (const float*)d_in[11];
    const float* ad2   = (const float*)d_in[12];
    const float* b2    = (const float*)d_in[13];
    float* out = (float*)d_out;

    const int E = in_sizes[1] / 2;
    const int ETOT = E + N;

    char* p = (char*)d_ws;
    auto alloc = [&](size_t bytes) {
        void* r = (void*)p;
        p += (bytes + 255) & ~(size_t)255;
        return r;
    };
    _Float16* xp    = (_Float16*)alloc((size_t)N * 128 * 2);
    _Float16* hbuf  = (_Float16*)alloc((size_t)N * 128 * 2);
    float* als      = (float*)alloc((size_t)N * 4 * 4);
    float* ald      = (float*)alloc((size_t)N * 4 * 4);
    int*   rowptr   = (int*)alloc((size_t)(N + 1) * 4);
    int*   ssrc     = (int*)alloc((size_t)ETOT * 4);
    int*   tmp      = (int*)alloc((size_t)ETOT * 4);
    int*   bucketCnt= (int*)alloc((size_t)NBUCK * 4);
    int*   bstart   = (int*)alloc((size_t)(NBUCK + 1) * 4);
    int*   gcur     = (int*)alloc((size_t)NBUCK * 4);
    _Float16* wt0   = (_Float16*)alloc((size_t)128 * 128 * 2);
    _Float16* wt1   = (_Float16*)alloc((size_t)128 * 128 * 2);
    _Float16* wt2   = (_Float16*)alloc((size_t)128 * 64 * 2);

    // ---- W transposes + bucketCnt zeroing ----
    k_wt3<<<(WT_TOT + 255) / 256, 256, 0, stream>>>(W0, W1, W2, wt0, wt1, wt2, bucketCnt);

    // ---- CSR build (bucket sort) ----
    const int PB = (ETOT + 4095) / 4096;
    k_bcount<<<PB, 256, 0, stream>>>(ei, E, ETOT, bucketCnt);
    k_bscan<<<1, 256, 0, stream>>>(bucketCnt, bstart, gcur, ETOT);
    k_bplace<<<PB, 256, 0, stream>>>(ei, E, ETOT, gcur, tmp);
    k_bfinal<<<NBUCK, 256, 0, stream>>>(tmp, bstart, rowptr, ssrc, N);

    const int gGemm = (N + 63) / 64;
    const int ngrp  = (N + 3) / 4;

    // ---- layer 0: 128 -> 4x32, ELU ----
    k_gemm<128, 4, false><<<gGemm, 256, 0, stream>>>(x, wt0, as0, ad0, xp, als, ald, N);
    k_agg<128, 4, true, true><<<ngrp, 256, 0, stream>>>(xp, als, ald, rowptr, ssrc, b0, hbuf, N, 0);
    k_agg<128, 4, true, true><<<ngrp, 256, 0, stream>>>(xp, als, ald, rowptr, ssrc, b0, hbuf, N, 1);

    // ---- layer 1: 128 -> 4x32, ELU ----
    k_gemm<128, 4, true><<<gGemm, 256, 0, stream>>>(hbuf, wt1, as1, ad1, xp, als, ald, N);
    k_agg<128, 4, true, true><<<ngrp, 256, 0, stream>>>(xp, als, ald, rowptr, ssrc, b1, hbuf, N, 0);
    k_agg<128, 4, true, true><<<ngrp, 256, 0, stream>>>(xp, als, ald, rowptr, ssrc, b1, hbuf, N, 1);

    // ---- layer 2: 128 -> 1x64, no ELU ----
    k_gemm<64, 1, true><<<gGemm, 256, 0, stream>>>(hbuf, wt2, as2, ad2, xp, als, ald, N);
    k_agg<64, 1, false, false><<<ngrp, 256, 0, stream>>>(xp, als, ald, rowptr, ssrc, b2, out, N, 0);
    k_agg<64, 1, false, false><<<ngrp, 256, 0, stream>>>(xp, als, ald, rowptr, ssrc, b2, out, N, 1);
}

// Round 12
// 321.470 us; speedup vs baseline: 3.2877x; 1.1998x over previous
//
#include <hip/hip_runtime.h>
#include <math.h>

// ---------------------------------------------------------------------------
// GAT (3-layer PyG GATConv, eval) on MI355X.
//   CSR build: two-level bucket sort (coalesced).
//   per layer: k_gemm = fp16 MFMA (16x16x32_f16, fp32 acc) + fused logits,
//              xp row-major fp16;
//              k_agg  = single-pass segment softmax aggregation, LPE lanes
//              (16B each) per edge, 4-unrolled trips, fma_mix inner loop.
// R12: R9 restored (R10/R11 restructures regressed; fetch = NXCD x WS is
//      compulsory). Layer-2 agg upgraded to 8-lane edge groups (32-edge
//      trips) via unified LPE = OUT/8 kernel.
// ---------------------------------------------------------------------------

#define N_NODES 100000
#define NBUCK ((N_NODES + 255) / 256)   // 391 buckets of 256 nodes
#define WT_ELEMS (16384 + 16384 + 8192) // wt0 + wt1 + wt2 elements
#define WT_TOT (WT_ELEMS + NBUCK)       // + bucketCnt zeroing

typedef __attribute__((ext_vector_type(4))) _Float16 half4;
typedef __attribute__((ext_vector_type(8))) _Float16 half8;
typedef __attribute__((ext_vector_type(4))) float f32x4;

// fma_mix: alo += s * f16lo(u); ahi += s * f16hi(u)   (exact: f16 widened)
__device__ inline void fmamix2(float& alo, float& ahi, float s, unsigned u) {
    asm("v_fma_mix_f32 %0, %1, %2, %0 op_sel_hi:[0,1,0]" : "+v"(alo) : "v"(s), "v"(u));
    asm("v_fma_mix_f32 %0, %1, %2, %0 op_sel:[0,1,0] op_sel_hi:[0,1,0]" : "+v"(ahi) : "v"(s), "v"(u));
}

// ------------------------------ CSR build ----------------------------------

__global__ __launch_bounds__(256) void k_bcount(const int* __restrict__ ei, int E, int ETOT,
                                                int* __restrict__ bucketCnt) {
    __shared__ int h[NBUCK];
    for (int b = threadIdx.x; b < NBUCK; b += 256) h[b] = 0;
    __syncthreads();
    const int base = blockIdx.x * 4096;
#pragma unroll
    for (int j = 0; j < 16; ++j) {
        int idx = base + j * 256 + threadIdx.x;
        if (idx < ETOT) {
            int dst = (idx < E) ? ei[E + idx] : (idx - E);
            atomicAdd(&h[dst >> 8], 1);
        }
    }
    __syncthreads();
    for (int b = threadIdx.x; b < NBUCK; b += 256)
        if (h[b]) atomicAdd(&bucketCnt[b], h[b]);
}

__global__ __launch_bounds__(256) void k_bscan(const int* __restrict__ bucketCnt,
                                               int* __restrict__ bstart,
                                               int* __restrict__ gcur, int ETOT) {
    __shared__ int lds[512];
    const int t = threadIdx.x;
    lds[t] = (t < NBUCK) ? bucketCnt[t] : 0;
    lds[t + 256] = (t + 256 < NBUCK) ? bucketCnt[t + 256] : 0;
    __syncthreads();
    for (int d = 1; d < 512; d <<= 1) {
        int v0 = (t >= d) ? lds[t - d] : 0;
        int v1 = (t + 256 >= d) ? lds[t + 256 - d] : 0;
        __syncthreads();
        lds[t] += v0;
        lds[t + 256] += v1;
        __syncthreads();
    }
    int e0 = (t == 0) ? 0 : lds[t - 1];
    int e1 = lds[t + 255];
    if (t < NBUCK)       { bstart[t] = e0;       gcur[t] = e0; }
    if (t + 256 < NBUCK) { bstart[t + 256] = e1; gcur[t + 256] = e1; }
    if (t == 0) bstart[NBUCK] = ETOT;
}

__global__ __launch_bounds__(256) void k_bplace(const int* __restrict__ ei, int E, int ETOT,
                                                int* __restrict__ gcur, int* __restrict__ tmp) {
    __shared__ int h[NBUCK];
    __shared__ int cur[NBUCK];
    for (int b = threadIdx.x; b < NBUCK; b += 256) h[b] = 0;
    __syncthreads();
    const int base = blockIdx.x * 4096;
    int pk[16], bk[16];
#pragma unroll
    for (int j = 0; j < 16; ++j) {
        int idx = base + j * 256 + threadIdx.x;
        bk[j] = -1;
        if (idx < ETOT) {
            int s, d;
            if (idx < E) { s = ei[idx]; d = ei[E + idx]; }
            else         { s = idx - E; d = idx - E; }
            bk[j] = d >> 8;
            pk[j] = s | ((d & 255) << 17);
            atomicAdd(&h[bk[j]], 1);
        }
    }
    __syncthreads();
    for (int b = threadIdx.x; b < NBUCK; b += 256)
        cur[b] = h[b] ? atomicAdd(&gcur[b], h[b]) : 0;
    __syncthreads();
#pragma unroll
    for (int j = 0; j < 16; ++j) {
        if (bk[j] >= 0) {
            int pos = atomicAdd(&cur[bk[j]], 1);
            tmp[pos] = pk[j];
        }
    }
}

__global__ __launch_bounds__(256) void k_bfinal(const int* __restrict__ tmp,
                                                const int* __restrict__ bstart,
                                                int* __restrict__ rowptr,
                                                int* __restrict__ ssrc, int N) {
    __shared__ int cnt[256];
    __shared__ int cur[256];
    const int t = threadIdx.x;
    const int b = blockIdx.x;
    const int s0 = bstart[b], s1 = bstart[b + 1];
    cnt[t] = 0;
    __syncthreads();
    for (int e = s0 + t; e < s1; e += 256)
        atomicAdd(&cnt[tmp[e] >> 17], 1);
    __syncthreads();
    int c0 = cnt[t];
    for (int d = 1; d < 256; d <<= 1) {
        int v = (t >= d) ? cnt[t - d] : 0;
        __syncthreads();
        cnt[t] += v;
        __syncthreads();
    }
    int excl = cnt[t] - c0;
    int node = b * 256 + t;
    if (node <= N) rowptr[node] = s0 + excl;
    cur[t] = excl;
    __syncthreads();
    for (int e = s0 + t; e < s1; e += 256) {
        int p = tmp[e];
        int pos = atomicAdd(&cur[p >> 17], 1);
        ssrc[s0 + pos] = p & 0x1FFFF;
    }
}

// ------------------- W transposes to fp16 (+ bucketCnt zero) ----------------
__global__ void k_wt3(const float* __restrict__ W0, const float* __restrict__ W1,
                      const float* __restrict__ W2, _Float16* __restrict__ wt0,
                      _Float16* __restrict__ wt1, _Float16* __restrict__ wt2,
                      int* __restrict__ bucketCnt) {
    int idx = blockIdx.x * 256 + threadIdx.x;
    if (idx < 16384) {
        int k = idx >> 7, n = idx & 127;
        wt0[n * 128 + k] = (_Float16)W0[idx];
    } else if (idx < 32768) {
        int i = idx - 16384;
        int k = i >> 7, n = i & 127;
        wt1[n * 128 + k] = (_Float16)W1[i];
    } else if (idx < WT_ELEMS) {
        int i = idx - 32768;
        int k = i >> 6, n = i & 63;
        wt2[n * 128 + k] = (_Float16)W2[i];
    } else if (idx < WT_TOT) {
        bucketCnt[idx - WT_ELEMS] = 0;
    }
}

// ------------------------------ MFMA GEMM + logits --------------------------
// xp[N][OUT] row-major fp16. C/D layout: col = lane&15, row = (lane>>4)*4+reg.
template <int OUT, int H, bool INF16>
__global__ __launch_bounds__(256) void k_gemm(const void* __restrict__ Xv_,
                                              const _Float16* __restrict__ Wt,
                                              const float* __restrict__ a_src,
                                              const float* __restrict__ a_dst,
                                              _Float16* __restrict__ XP,
                                              float* __restrict__ al_s,
                                              float* __restrict__ al_d, int N) {
    constexpr int NT = OUT / 16;
    constexpr int C = OUT / H;
    constexpr int LDH = 136;
    __shared__ _Float16 As[64 * LDH];
    __shared__ _Float16 Ws[OUT * LDH];
    const int tid = threadIdx.x;
    const int row0 = blockIdx.x * 64;

    for (int c = tid; c < OUT * 16; c += 256) {
        int r = c >> 4, kc = c & 15;
        *(half8*)&Ws[r * LDH + kc * 8] = *(const half8*)(Wt + r * 128 + kc * 8);
    }
    for (int c = tid; c < 64 * 16; c += 256) {
        int r = c >> 4, kc = c & 15;
        int grow = row0 + r;
        half8 hv;
        if (grow < N) {
            if constexpr (INF16) {
                hv = *(const half8*)((const _Float16*)Xv_ + (size_t)grow * 128 + kc * 8);
            } else {
                const float4* xr = (const float4*)((const float*)Xv_ + (size_t)grow * 128 + kc * 8);
                float4 x0 = xr[0], x1 = xr[1];
                hv[0] = (_Float16)x0.x; hv[1] = (_Float16)x0.y;
                hv[2] = (_Float16)x0.z; hv[3] = (_Float16)x0.w;
                hv[4] = (_Float16)x1.x; hv[5] = (_Float16)x1.y;
                hv[6] = (_Float16)x1.z; hv[7] = (_Float16)x1.w;
            }
        } else {
#pragma unroll
            for (int j = 0; j < 8; ++j) hv[j] = (_Float16)0.f;
        }
        *(half8*)&As[r * LDH + kc * 8] = hv;
    }
    __syncthreads();

    const int w = tid >> 6;
    const int l = tid & 63;
    const int lm = l & 15;
    const int lk = l >> 4;

    f32x4 acc[NT];
#pragma unroll
    for (int nt = 0; nt < NT; ++nt) acc[nt] = {0.f, 0.f, 0.f, 0.f};

#pragma unroll
    for (int ks = 0; ks < 4; ++ks) {
        half8 av = *(const half8*)&As[(w * 16 + lm) * LDH + ks * 32 + lk * 8];
#pragma unroll
        for (int nt = 0; nt < NT; ++nt) {
            half8 bv = *(const half8*)&Ws[(nt * 16 + lm) * LDH + ks * 32 + lk * 8];
            acc[nt] = __builtin_amdgcn_mfma_f32_16x16x32_f16(av, bv, acc[nt], 0, 0, 0);
        }
    }

    float avs[NT], avd[NT];
#pragma unroll
    for (int nt = 0; nt < NT; ++nt) {
        avs[nt] = a_src[nt * 16 + lm];
        avd[nt] = a_dst[nt * 16 + lm];
    }

#pragma unroll
    for (int r = 0; r < 4; ++r) {
        int grow = row0 + w * 16 + lk * 4 + r;
        bool ok = grow < N;
#pragma unroll
        for (int nt = 0; nt < NT; ++nt)
            if (ok) XP[(size_t)grow * OUT + nt * 16 + lm] = (_Float16)acc[nt][r];

        float ps[H], pd[H];
#pragma unroll
        for (int h = 0; h < H; ++h) { ps[h] = 0.f; pd[h] = 0.f; }
#pragma unroll
        for (int nt = 0; nt < NT; ++nt) {
            int h = (nt * 16) / C;
            ps[h] += acc[nt][r] * avs[nt];
            pd[h] += acc[nt][r] * avd[nt];
        }
#pragma unroll
        for (int h = 0; h < H; ++h) {
#pragma unroll
            for (int o = 8; o >= 1; o >>= 1) {
                ps[h] += __shfl_xor(ps[h], o);
                pd[h] += __shfl_xor(pd[h], o);
            }
        }
        if (ok && lm == 0) {
#pragma unroll
            for (int h = 0; h < H; ++h) {
                al_s[(size_t)grow * H + h] = ps[h];
                al_d[(size_t)grow * H + h] = pd[h];
            }
        }
    }
}

// --------------------------- softmax + aggregate ----------------------------
// one wave per node. LPE = OUT/8 lanes (16B each) per edge; NG = 64/LPE edge
// slots; 4-unrolled main trips (16 or 32 edges in flight). inline per-lane
// alpha + v_fma_mix_f32 gather-accumulate.
template <int OUT, int H, bool ELU, bool OUTF16>
__global__ __launch_bounds__(256) void k_agg(const _Float16* __restrict__ xp,
                                             const float* __restrict__ al_s,
                                             const float* __restrict__ al_d,
                                             const int* __restrict__ rowptr,
                                             const int* __restrict__ ssrc,
                                             const float* __restrict__ bias,
                                             void* __restrict__ out_, int N) {
    constexpr int C = OUT / H;
    constexpr int LPE = OUT / 8;   // lanes per edge (16 or 8)
    constexpr int NG = 64 / LPE;   // edge slots per wave (4 or 8)
    const int wid = threadIdx.x >> 6;
    const int lane = threadIdx.x & 63;
    const int g = lane / LPE;      // edge slot
    const int cl = lane % LPE;     // channel lane within edge
    const int node = blockIdx.x * 4 + wid;
    if (node >= N) return;
    const int rs = rowptr[node];
    const int re = rowptr[node + 1];

    const int c0 = cl * 8;
    const int head = c0 / C;
    const float adh = al_d[(unsigned)node * H + head];

    float ssum = 0.f;
    float acc[8];
#pragma unroll
    for (int j = 0; j < 8; ++j) acc[j] = 0.f;

    auto edge = [&](int idx) {
        int s = ssrc[idx];
        float e = al_s[(unsigned)s * H + head] + adh;
        e = e > 0.f ? e : 0.2f * e;
        float a = __expf(e);
        ssum += a;
        uint4 u = *(const uint4*)(xp + (unsigned)s * OUT + c0);
        fmamix2(acc[0], acc[1], a, u.x);
        fmamix2(acc[2], acc[3], a, u.y);
        fmamix2(acc[4], acc[5], a, u.z);
        fmamix2(acc[6], acc[7], a, u.w);
    };

    int i = rs;
    for (; i + 4 * NG <= re; i += 4 * NG) {
        edge(i + g); edge(i + g + NG); edge(i + g + 2 * NG); edge(i + g + 3 * NG);
    }
    for (; i + g < re; i += NG) {
        edge(i + g);
    }

    // reduce across edge slots (cl preserved)
#pragma unroll
    for (int o = LPE; o <= 32; o <<= 1) {
        ssum += __shfl_xor(ssum, o);
#pragma unroll
        for (int j = 0; j < 8; ++j) acc[j] += __shfl_xor(acc[j], o);
    }

    if (g == 0) {   // lanes 0..LPE-1 write 8 channels each
        float inv = 1.f / (ssum + 1e-16f);
        float o[8];
#pragma unroll
        for (int j = 0; j < 8; ++j) {
            o[j] = acc[j] * inv + bias[c0 + j];
            if constexpr (ELU) o[j] = o[j] > 0.f ? o[j] : (__expf(o[j]) - 1.f);
        }
        if constexpr (OUTF16) {
            _Float16* op = (_Float16*)out_ + (size_t)node * OUT + c0;
            half8 hv;
#pragma unroll
            for (int j = 0; j < 8; ++j) hv[j] = (_Float16)o[j];
            *(half8*)op = hv;
        } else {
            float* op = (float*)out_ + (size_t)node * OUT + c0;
            *(float4*)op = make_float4(o[0], o[1], o[2], o[3]);
            *(float4*)(op + 4) = make_float4(o[4], o[5], o[6], o[7]);
        }
    }
}

// ------------------------------ launch --------------------------------------

extern "C" void kernel_launch(void* const* d_in, const int* in_sizes, int n_in,
                              void* d_out, int out_size, void* d_ws, size_t ws_size,
                              hipStream_t stream) {
    const int N = N_NODES;
    const float* x     = (const float*)d_in[0];
    const int*   ei    = (const int*)d_in[1];
    const float* W0    = (const float*)d_in[2];
    const float* as0   = (const float*)d_in[3];
    const float* ad0   = (const float*)d_in[4];
    const float* b0    = (const float*)d_in[5];
    const float* W1    = (const float*)d_in[6];
    const float* as1   = (const float*)d_in[7];
    const float* ad1   = (const float*)d_in[8];
    const float* b1    = (const float*)d_in[9];
    const float* W2    = (const float*)d_in[10];
    const float* as2   = (const float*)d_in[11];
    const float* ad2   = (const float*)d_in[12];
    const float* b2    = (const float*)d_in[13];
    float* out = (float*)d_out;

    const int E = in_sizes[1] / 2;
    const int ETOT = E + N;

    char* p = (char*)d_ws;
    auto alloc = [&](size_t bytes) {
        void* r = (void*)p;
        p += (bytes + 255) & ~(size_t)255;
        return r;
    };
    _Float16* xp    = (_Float16*)alloc((size_t)N * 128 * 2);
    _Float16* hbuf  = (_Float16*)alloc((size_t)N * 128 * 2);
    float* als      = (float*)alloc((size_t)N * 4 * 4);
    float* ald      = (float*)alloc((size_t)N * 4 * 4);
    int*   rowptr   = (int*)alloc((size_t)(N + 1) * 4);
    int*   ssrc     = (int*)alloc((size_t)ETOT * 4);
    int*   tmp      = (int*)alloc((size_t)ETOT * 4);
    int*   bucketCnt= (int*)alloc((size_t)NBUCK * 4);
    int*   bstart   = (int*)alloc((size_t)(NBUCK + 1) * 4);
    int*   gcur     = (int*)alloc((size_t)NBUCK * 4);
    _Float16* wt0   = (_Float16*)alloc((size_t)128 * 128 * 2);
    _Float16* wt1   = (_Float16*)alloc((size_t)128 * 128 * 2);
    _Float16* wt2   = (_Float16*)alloc((size_t)128 * 64 * 2);

    // ---- W transposes + bucketCnt zeroing ----
    k_wt3<<<(WT_TOT + 255) / 256, 256, 0, stream>>>(W0, W1, W2, wt0, wt1, wt2, bucketCnt);

    // ---- CSR build (bucket sort) ----
    const int PB = (ETOT + 4095) / 4096;
    k_bcount<<<PB, 256, 0, stream>>>(ei, E, ETOT, bucketCnt);
    k_bscan<<<1, 256, 0, stream>>>(bucketCnt, bstart, gcur, ETOT);
    k_bplace<<<PB, 256, 0, stream>>>(ei, E, ETOT, gcur, tmp);
    k_bfinal<<<NBUCK, 256, 0, stream>>>(tmp, bstart, rowptr, ssrc, N);

    const int gGemm = (N + 63) / 64;
    const int gAgg  = (N + 3) / 4;

    // ---- layer 0: 128 -> 4x32, ELU ----
    k_gemm<128, 4, false><<<gGemm, 256, 0, stream>>>(x, wt0, as0, ad0, xp, als, ald, N);
    k_agg<128, 4, true, true><<<gAgg, 256, 0, stream>>>(xp, als, ald, rowptr, ssrc, b0, hbuf, N);

    // ---- layer 1: 128 -> 4x32, ELU ----
    k_gemm<128, 4, true><<<gGemm, 256, 0, stream>>>(hbuf, wt1, as1, ad1, xp, als, ald, N);
    k_agg<128, 4, true, true><<<gAgg, 256, 0, stream>>>(xp, als, ald, rowptr, ssrc, b1, hbuf, N);

    // ---- layer 2: 128 -> 1x64, no ELU ----
    k_gemm<64, 1, true><<<gGemm, 256, 0, stream>>>(hbuf, wt2, as2, ad2, xp, als, ald, N);
    k_agg<64, 1, false, false><<<gAgg, 256, 0, stream>>>(xp, als, ald, rowptr, ssrc, b2, out, N);
}

// Round 13
// 318.126 us; speedup vs baseline: 3.3223x; 1.0105x over previous
//
#include <hip/hip_runtime.h>
#include <math.h>

// ---------------------------------------------------------------------------
// GAT (3-layer PyG GATConv, eval) on MI355X.
//   CSR build: two-level bucket sort (coalesced).
//   per layer: k_gemm = fp16 MFMA (16x16x32_f16, fp32 acc) + fused logits,
//              xp row-major fp16;
//              k_agg  = single-pass segment softmax aggregation, LPE lanes
//              (16B each) per edge, 8-unrolled trips, fma_mix inner loop.
// R13: agg pipeline deepened 4->8 trips (32/64 edges in flight); tail split.
// ---------------------------------------------------------------------------

#define N_NODES 100000
#define NBUCK ((N_NODES + 255) / 256)   // 391 buckets of 256 nodes
#define WT_ELEMS (16384 + 16384 + 8192) // wt0 + wt1 + wt2 elements
#define WT_TOT (WT_ELEMS + NBUCK)       // + bucketCnt zeroing

typedef __attribute__((ext_vector_type(4))) _Float16 half4;
typedef __attribute__((ext_vector_type(8))) _Float16 half8;
typedef __attribute__((ext_vector_type(4))) float f32x4;

// fma_mix: alo += s * f16lo(u); ahi += s * f16hi(u)   (exact: f16 widened)
__device__ inline void fmamix2(float& alo, float& ahi, float s, unsigned u) {
    asm("v_fma_mix_f32 %0, %1, %2, %0 op_sel_hi:[0,1,0]" : "+v"(alo) : "v"(s), "v"(u));
    asm("v_fma_mix_f32 %0, %1, %2, %0 op_sel:[0,1,0] op_sel_hi:[0,1,0]" : "+v"(ahi) : "v"(s), "v"(u));
}

// ------------------------------ CSR build ----------------------------------

__global__ __launch_bounds__(256) void k_bcount(const int* __restrict__ ei, int E, int ETOT,
                                                int* __restrict__ bucketCnt) {
    __shared__ int h[NBUCK];
    for (int b = threadIdx.x; b < NBUCK; b += 256) h[b] = 0;
    __syncthreads();
    const int base = blockIdx.x * 4096;
#pragma unroll
    for (int j = 0; j < 16; ++j) {
        int idx = base + j * 256 + threadIdx.x;
        if (idx < ETOT) {
            int dst = (idx < E) ? ei[E + idx] : (idx - E);
            atomicAdd(&h[dst >> 8], 1);
        }
    }
    __syncthreads();
    for (int b = threadIdx.x; b < NBUCK; b += 256)
        if (h[b]) atomicAdd(&bucketCnt[b], h[b]);
}

__global__ __launch_bounds__(256) void k_bscan(const int* __restrict__ bucketCnt,
                                               int* __restrict__ bstart,
                                               int* __restrict__ gcur, int ETOT) {
    __shared__ int lds[512];
    const int t = threadIdx.x;
    lds[t] = (t < NBUCK) ? bucketCnt[t] : 0;
    lds[t + 256] = (t + 256 < NBUCK) ? bucketCnt[t + 256] : 0;
    __syncthreads();
    for (int d = 1; d < 512; d <<= 1) {
        int v0 = (t >= d) ? lds[t - d] : 0;
        int v1 = (t + 256 >= d) ? lds[t + 256 - d] : 0;
        __syncthreads();
        lds[t] += v0;
        lds[t + 256] += v1;
        __syncthreads();
    }
    int e0 = (t == 0) ? 0 : lds[t - 1];
    int e1 = lds[t + 255];
    if (t < NBUCK)       { bstart[t] = e0;       gcur[t] = e0; }
    if (t + 256 < NBUCK) { bstart[t + 256] = e1; gcur[t + 256] = e1; }
    if (t == 0) bstart[NBUCK] = ETOT;
}

__global__ __launch_bounds__(256) void k_bplace(const int* __restrict__ ei, int E, int ETOT,
                                                int* __restrict__ gcur, int* __restrict__ tmp) {
    __shared__ int h[NBUCK];
    __shared__ int cur[NBUCK];
    for (int b = threadIdx.x; b < NBUCK; b += 256) h[b] = 0;
    __syncthreads();
    const int base = blockIdx.x * 4096;
    int pk[16], bk[16];
#pragma unroll
    for (int j = 0; j < 16; ++j) {
        int idx = base + j * 256 + threadIdx.x;
        bk[j] = -1;
        if (idx < ETOT) {
            int s, d;
            if (idx < E) { s = ei[idx]; d = ei[E + idx]; }
            else         { s = idx - E; d = idx - E; }
            bk[j] = d >> 8;
            pk[j] = s | ((d & 255) << 17);
            atomicAdd(&h[bk[j]], 1);
        }
    }
    __syncthreads();
    for (int b = threadIdx.x; b < NBUCK; b += 256)
        cur[b] = h[b] ? atomicAdd(&gcur[b], h[b]) : 0;
    __syncthreads();
#pragma unroll
    for (int j = 0; j < 16; ++j) {
        if (bk[j] >= 0) {
            int pos = atomicAdd(&cur[bk[j]], 1);
            tmp[pos] = pk[j];
        }
    }
}

__global__ __launch_bounds__(256) void k_bfinal(const int* __restrict__ tmp,
                                                const int* __restrict__ bstart,
                                                int* __restrict__ rowptr,
                                                int* __restrict__ ssrc, int N) {
    __shared__ int cnt[256];
    __shared__ int cur[256];
    const int t = threadIdx.x;
    const int b = blockIdx.x;
    const int s0 = bstart[b], s1 = bstart[b + 1];
    cnt[t] = 0;
    __syncthreads();
    for (int e = s0 + t; e < s1; e += 256)
        atomicAdd(&cnt[tmp[e] >> 17], 1);
    __syncthreads();
    int c0 = cnt[t];
    for (int d = 1; d < 256; d <<= 1) {
        int v = (t >= d) ? cnt[t - d] : 0;
        __syncthreads();
        cnt[t] += v;
        __syncthreads();
    }
    int excl = cnt[t] - c0;
    int node = b * 256 + t;
    if (node <= N) rowptr[node] = s0 + excl;
    cur[t] = excl;
    __syncthreads();
    for (int e = s0 + t; e < s1; e += 256) {
        int p = tmp[e];
        int pos = atomicAdd(&cur[p >> 17], 1);
        ssrc[s0 + pos] = p & 0x1FFFF;
    }
}

// ------------------- W transposes to fp16 (+ bucketCnt zero) ----------------
__global__ void k_wt3(const float* __restrict__ W0, const float* __restrict__ W1,
                      const float* __restrict__ W2, _Float16* __restrict__ wt0,
                      _Float16* __restrict__ wt1, _Float16* __restrict__ wt2,
                      int* __restrict__ bucketCnt) {
    int idx = blockIdx.x * 256 + threadIdx.x;
    if (idx < 16384) {
        int k = idx >> 7, n = idx & 127;
        wt0[n * 128 + k] = (_Float16)W0[idx];
    } else if (idx < 32768) {
        int i = idx - 16384;
        int k = i >> 7, n = i & 127;
        wt1[n * 128 + k] = (_Float16)W1[i];
    } else if (idx < WT_ELEMS) {
        int i = idx - 32768;
        int k = i >> 6, n = i & 63;
        wt2[n * 128 + k] = (_Float16)W2[i];
    } else if (idx < WT_TOT) {
        bucketCnt[idx - WT_ELEMS] = 0;
    }
}

// ------------------------------ MFMA GEMM + logits --------------------------
// xp[N][OUT] row-major fp16. C/D layout: col = lane&15, row = (lane>>4)*4+reg.
template <int OUT, int H, bool INF16>
__global__ __launch_bounds__(256) void k_gemm(const void* __restrict__ Xv_,
                                              const _Float16* __restrict__ Wt,
                                              const float* __restrict__ a_src,
                                              const float* __restrict__ a_dst,
                                              _Float16* __restrict__ XP,
                                              float* __restrict__ al_s,
                                              float* __restrict__ al_d, int N) {
    constexpr int NT = OUT / 16;
    constexpr int C = OUT / H;
    constexpr int LDH = 136;
    __shared__ _Float16 As[64 * LDH];
    __shared__ _Float16 Ws[OUT * LDH];
    const int tid = threadIdx.x;
    const int row0 = blockIdx.x * 64;

    for (int c = tid; c < OUT * 16; c += 256) {
        int r = c >> 4, kc = c & 15;
        *(half8*)&Ws[r * LDH + kc * 8] = *(const half8*)(Wt + r * 128 + kc * 8);
    }
    for (int c = tid; c < 64 * 16; c += 256) {
        int r = c >> 4, kc = c & 15;
        int grow = row0 + r;
        half8 hv;
        if (grow < N) {
            if constexpr (INF16) {
                hv = *(const half8*)((const _Float16*)Xv_ + (size_t)grow * 128 + kc * 8);
            } else {
                const float4* xr = (const float4*)((const float*)Xv_ + (size_t)grow * 128 + kc * 8);
                float4 x0 = xr[0], x1 = xr[1];
                hv[0] = (_Float16)x0.x; hv[1] = (_Float16)x0.y;
                hv[2] = (_Float16)x0.z; hv[3] = (_Float16)x0.w;
                hv[4] = (_Float16)x1.x; hv[5] = (_Float16)x1.y;
                hv[6] = (_Float16)x1.z; hv[7] = (_Float16)x1.w;
            }
        } else {
#pragma unroll
            for (int j = 0; j < 8; ++j) hv[j] = (_Float16)0.f;
        }
        *(half8*)&As[r * LDH + kc * 8] = hv;
    }
    __syncthreads();

    const int w = tid >> 6;
    const int l = tid & 63;
    const int lm = l & 15;
    const int lk = l >> 4;

    f32x4 acc[NT];
#pragma unroll
    for (int nt = 0; nt < NT; ++nt) acc[nt] = {0.f, 0.f, 0.f, 0.f};

#pragma unroll
    for (int ks = 0; ks < 4; ++ks) {
        half8 av = *(const half8*)&As[(w * 16 + lm) * LDH + ks * 32 + lk * 8];
#pragma unroll
        for (int nt = 0; nt < NT; ++nt) {
            half8 bv = *(const half8*)&Ws[(nt * 16 + lm) * LDH + ks * 32 + lk * 8];
            acc[nt] = __builtin_amdgcn_mfma_f32_16x16x32_f16(av, bv, acc[nt], 0, 0, 0);
        }
    }

    float avs[NT], avd[NT];
#pragma unroll
    for (int nt = 0; nt < NT; ++nt) {
        avs[nt] = a_src[nt * 16 + lm];
        avd[nt] = a_dst[nt * 16 + lm];
    }

#pragma unroll
    for (int r = 0; r < 4; ++r) {
        int grow = row0 + w * 16 + lk * 4 + r;
        bool ok = grow < N;
#pragma unroll
        for (int nt = 0; nt < NT; ++nt)
            if (ok) XP[(size_t)grow * OUT + nt * 16 + lm] = (_Float16)acc[nt][r];

        float ps[H], pd[H];
#pragma unroll
        for (int h = 0; h < H; ++h) { ps[h] = 0.f; pd[h] = 0.f; }
#pragma unroll
        for (int nt = 0; nt < NT; ++nt) {
            int h = (nt * 16) / C;
            ps[h] += acc[nt][r] * avs[nt];
            pd[h] += acc[nt][r] * avd[nt];
        }
#pragma unroll
        for (int h = 0; h < H; ++h) {
#pragma unroll
            for (int o = 8; o >= 1; o >>= 1) {
                ps[h] += __shfl_xor(ps[h], o);
                pd[h] += __shfl_xor(pd[h], o);
            }
        }
        if (ok && lm == 0) {
#pragma unroll
            for (int h = 0; h < H; ++h) {
                al_s[(size_t)grow * H + h] = ps[h];
                al_d[(size_t)grow * H + h] = pd[h];
            }
        }
    }
}

// --------------------------- softmax + aggregate ----------------------------
// one wave per node. LPE = OUT/8 lanes (16B each) per edge; NG = 64/LPE edge
// slots; 8-unrolled main trips (32 or 64 edges in flight). inline per-lane
// alpha + v_fma_mix_f32 gather-accumulate.
template <int OUT, int H, bool ELU, bool OUTF16>
__global__ __launch_bounds__(256) void k_agg(const _Float16* __restrict__ xp,
                                             const float* __restrict__ al_s,
                                             const float* __restrict__ al_d,
                                             const int* __restrict__ rowptr,
                                             const int* __restrict__ ssrc,
                                             const float* __restrict__ bias,
                                             void* __restrict__ out_, int N) {
    constexpr int C = OUT / H;
    constexpr int LPE = OUT / 8;   // lanes per edge (16 or 8)
    constexpr int NG = 64 / LPE;   // edge slots per wave (4 or 8)
    const int wid = threadIdx.x >> 6;
    const int lane = threadIdx.x & 63;
    const int g = lane / LPE;      // edge slot
    const int cl = lane % LPE;     // channel lane within edge
    const int node = blockIdx.x * 4 + wid;
    if (node >= N) return;
    const int rs = rowptr[node];
    const int re = rowptr[node + 1];

    const int c0 = cl * 8;
    const int head = c0 / C;
    const float adh = al_d[(unsigned)node * H + head];

    float ssum = 0.f;
    float acc[8];
#pragma unroll
    for (int j = 0; j < 8; ++j) acc[j] = 0.f;

    auto edge = [&](int idx) {
        int s = ssrc[idx];
        float e = al_s[(unsigned)s * H + head] + adh;
        e = e > 0.f ? e : 0.2f * e;
        float a = __expf(e);
        ssum += a;
        uint4 u = *(const uint4*)(xp + (unsigned)s * OUT + c0);
        fmamix2(acc[0], acc[1], a, u.x);
        fmamix2(acc[2], acc[3], a, u.y);
        fmamix2(acc[4], acc[5], a, u.z);
        fmamix2(acc[6], acc[7], a, u.w);
    };

    int i = rs;
    // deep main loop: 8 trips unrolled -> 8*NG edges (32 or 64) in flight
    for (; i + 8 * NG <= re; i += 8 * NG) {
#pragma unroll
        for (int t = 0; t < 8; ++t) edge(i + g + t * NG);
    }
    // middle: 2 trips
    for (; i + 2 * NG <= re; i += 2 * NG) {
        edge(i + g); edge(i + g + NG);
    }
    // tail
    for (; i + g < re; i += NG) {
        edge(i + g);
    }

    // reduce across edge slots (cl preserved)
#pragma unroll
    for (int o = LPE; o <= 32; o <<= 1) {
        ssum += __shfl_xor(ssum, o);
#pragma unroll
        for (int j = 0; j < 8; ++j) acc[j] += __shfl_xor(acc[j], o);
    }

    if (g == 0) {   // lanes 0..LPE-1 write 8 channels each
        float inv = 1.f / (ssum + 1e-16f);
        float o[8];
#pragma unroll
        for (int j = 0; j < 8; ++j) {
            o[j] = acc[j] * inv + bias[c0 + j];
            if constexpr (ELU) o[j] = o[j] > 0.f ? o[j] : (__expf(o[j]) - 1.f);
        }
        if constexpr (OUTF16) {
            _Float16* op = (_Float16*)out_ + (size_t)node * OUT + c0;
            half8 hv;
#pragma unroll
            for (int j = 0; j < 8; ++j) hv[j] = (_Float16)o[j];
            *(half8*)op = hv;
        } else {
            float* op = (float*)out_ + (size_t)node * OUT + c0;
            *(float4*)op = make_float4(o[0], o[1], o[2], o[3]);
            *(float4*)(op + 4) = make_float4(o[4], o[5], o[6], o[7]);
        }
    }
}

// ------------------------------ launch --------------------------------------

extern "C" void kernel_launch(void* const* d_in, const int* in_sizes, int n_in,
                              void* d_out, int out_size, void* d_ws, size_t ws_size,
                              hipStream_t stream) {
    const int N = N_NODES;
    const float* x     = (const float*)d_in[0];
    const int*   ei    = (const int*)d_in[1];
    const float* W0    = (const float*)d_in[2];
    const float* as0   = (const float*)d_in[3];
    const float* ad0   = (const float*)d_in[4];
    const float* b0    = (const float*)d_in[5];
    const float* W1    = (const float*)d_in[6];
    const float* as1   = (const float*)d_in[7];
    const float* ad1   = (const float*)d_in[8];
    const float* b1    = (const float*)d_in[9];
    const float* W2    = (const float*)d_in[10];
    const float* as2   = (const float*)d_in[11];
    const float* ad2   = (const float*)d_in[12];
    const float* b2    = (const float*)d_in[13];
    float* out = (float*)d_out;

    const int E = in_sizes[1] / 2;
    const int ETOT = E + N;

    char* p = (char*)d_ws;
    auto alloc = [&](size_t bytes) {
        void* r = (void*)p;
        p += (bytes + 255) & ~(size_t)255;
        return r;
    };
    _Float16* xp    = (_Float16*)alloc((size_t)N * 128 * 2);
    _Float16* hbuf  = (_Float16*)alloc((size_t)N * 128 * 2);
    float* als      = (float*)alloc((size_t)N * 4 * 4);
    float* ald      = (float*)alloc((size_t)N * 4 * 4);
    int*   rowptr   = (int*)alloc((size_t)(N + 1) * 4);
    int*   ssrc     = (int*)alloc((size_t)ETOT * 4);
    int*   tmp      = (int*)alloc((size_t)ETOT * 4);
    int*   bucketCnt= (int*)alloc((size_t)NBUCK * 4);
    int*   bstart   = (int*)alloc((size_t)(NBUCK + 1) * 4);
    int*   gcur     = (int*)alloc((size_t)NBUCK * 4);
    _Float16* wt0   = (_Float16*)alloc((size_t)128 * 128 * 2);
    _Float16* wt1   = (_Float16*)alloc((size_t)128 * 128 * 2);
    _Float16* wt2   = (_Float16*)alloc((size_t)128 * 64 * 2);

    // ---- W transposes + bucketCnt zeroing ----
    k_wt3<<<(WT_TOT + 255) / 256, 256, 0, stream>>>(W0, W1, W2, wt0, wt1, wt2, bucketCnt);

    // ---- CSR build (bucket sort) ----
    const int PB = (ETOT + 4095) / 4096;
    k_bcount<<<PB, 256, 0, stream>>>(ei, E, ETOT, bucketCnt);
    k_bscan<<<1, 256, 0, stream>>>(bucketCnt, bstart, gcur, ETOT);
    k_bplace<<<PB, 256, 0, stream>>>(ei, E, ETOT, gcur, tmp);
    k_bfinal<<<NBUCK, 256, 0, stream>>>(tmp, bstart, rowptr, ssrc, N);

    const int gGemm = (N + 63) / 64;
    const int gAgg  = (N + 3) / 4;

    // ---- layer 0: 128 -> 4x32, ELU ----
    k_gemm<128, 4, false><<<gGemm, 256, 0, stream>>>(x, wt0, as0, ad0, xp, als, ald, N);
    k_agg<128, 4, true, true><<<gAgg, 256, 0, stream>>>(xp, als, ald, rowptr, ssrc, b0, hbuf, N);

    // ---- layer 1: 128 -> 4x32, ELU ----
    k_gemm<128, 4, true><<<gGemm, 256, 0, stream>>>(hbuf, wt1, as1, ad1, xp, als, ald, N);
    k_agg<128, 4, true, true><<<gAgg, 256, 0, stream>>>(xp, als, ald, rowptr, ssrc, b1, hbuf, N);

    // ---- layer 2: 128 -> 1x64, no ELU ----
    k_gemm<64, 1, true><<<gGemm, 256, 0, stream>>>(hbuf, wt2, as2, ad2, xp, als, ald, N);
    k_agg<64, 1, false, false><<<gAgg, 256, 0, stream>>>(xp, als, ald, rowptr, ssrc, b2, out, N);
}